// Round 9
// baseline (262.000 us; speedup 1.0000x reference)
//
#include <hip/hip_runtime.h>
#include <hip/hip_bf16.h>

typedef __attribute__((ext_vector_type(8))) short  short8;
typedef __attribute__((ext_vector_type(4))) short  short4v;
typedef __attribute__((ext_vector_type(4))) float  float4v;
typedef __attribute__((ext_vector_type(4))) unsigned short ushort4v;

#define NC    8192
#define TPIX  784      // 28*28
#define NB    8

// ws layout (bytes)
#define WS_M2    0                 // bf16 [800][160]   = 256000
#define WS_O     262144            // f32  [8192]       = 32768
#define WS_ZACC  294912            // f32  [8][784]     = 25088
#define WS_DACC  320000            // f32  [8][784]     = 25088
#define WS_ZPOS  345088            // f32  [8][25][25]  = 20000
#define WS_ZERO_OFF WS_ZACC
#define WS_ZERO_LEN 70176
#define WS_STUDB 365568            // bf16 [65536][160] = 20971520
#define WS_NEED_MID  (WS_STUDB + 65536LL*320)

__device__ __forceinline__ unsigned short bf16rne(float f) {
    unsigned int u = __float_as_uint(f);
    u = (u + 0x7FFFu + ((u >> 16) & 1u)) >> 16;
    return (unsigned short)u;
}

__device__ __forceinline__ short8 cvt8(float4v a, float4v b) {
    union { __hip_bfloat162 h[4]; short8 s; } u;
    u.h[0] = __float22bfloat162_rn(float2{a[0], a[1]});
    u.h[1] = __float22bfloat162_rn(float2{a[2], a[3]});
    u.h[2] = __float22bfloat162_rn(float2{b[0], b[1]});
    u.h[3] = __float22bfloat162_rn(float2{b[2], b[3]});
    return u.s;
}

__device__ __forceinline__ float bf2f(unsigned short h) {
    return __uint_as_float(((unsigned int)h) << 16);
}

// ---------------- kernel 1: combined prep -------------------------------------------
// blocks [0,5120): student -> padded bf16 [65536][160] + o[c]
// blocks [5120,5620): M2' = 10*K[y,v]*K[x,u], bf16 [800][160] (rows >=784 zero)
__launch_bounds__(256)
__global__ void k_prep(const float* __restrict__ student, const float* __restrict__ center,
                       unsigned short* __restrict__ studb, float* __restrict__ o,
                       unsigned short* __restrict__ m2) {
    const int bid = blockIdx.x;
    if (bid < 5120) {
        const int tid = bid * 256 + threadIdx.x;      // 0 .. 1310719
        const int row = tid / 20, ch = tid % 20;
        short8 hv = {0,0,0,0,0,0,0,0};
        if (ch < 18) {
            const float* src = student + (long long)row * 144 + ch * 8;
            hv = cvt8(*(const float4v*)(src), *(const float4v*)(src + 4));
        }
        *(short8*)(studb + (long long)row * 160 + ch * 8) = hv;
        if (ch == 0 && row < NC)
            o[row] = fmaf(36.0673762f, center[row], 233.7165966f);
    } else {
        const int idx = (bid - 5120) * 256 + threadIdx.x;   // 0 .. 127999
        const int p = idx / 160, sp = idx % 160;            // p 0..799
        int y = p / 28, x = p % 28;
        float val = 0.f;
        if (sp < 144 && p < TPIX) {
            int v = sp / 12, u = sp % 12;
            float kyv = 0.f, kxu = 0.f;
            for (int a = 0; a < 25; ++a) {
                float ctc = 0.9f + 1.05f * (float)a;
                int   i0  = (int)ctc; float wt = ctc - (float)i0;
                float Ay  = (i0 == y) ? (1.f - wt) : ((i0 + 1 == y) ? wt : 0.f);
                float Ax  = (i0 == x) ? (1.f - wt) : ((i0 + 1 == x) ? wt : 0.f);
                float csc = 0.7f + 0.4f * (float)a;
                int   j0  = (int)csc; float wsv = csc - (float)j0;
                float Bv  = (j0 == v) ? (1.f - wsv) : ((j0 + 1 == v) ? wsv : 0.f);
                float Bu  = (j0 == u) ? (1.f - wsv) : ((j0 + 1 == u) ? wsv : 0.f);
                kyv += Ay * Bv;
                kxu += Ax * Bu;
            }
            val = 10.f * kyv * kxu;
        }
        m2[p * 160 + sp] = bf16rne(val);
    }
}

// ---------------- kernel 2: single-shot fused GEMM + softmax reduce (de-looped) --------
// One 32-channel slab per block: the R5 loop body with cc -> blockIdx.y. Short-lived
// blocks maximize load-burst turnover (TLP instead of per-thread loop ILP).
// grid (7 px, 256 cg, 8 b) = 14336 blocks, 256 thr (4 waves).
// Wave owns 2 p-tiles; lane (g,l15) owns (p = p0 + 4g + i, c in {cA, cB}).
__launch_bounds__(256)
__global__ void k_main_s(const float* __restrict__ teacher,
                         const unsigned short* __restrict__ m2,
                         const unsigned short* __restrict__ studb,
                         const float* __restrict__ o,
                         float* __restrict__ zacc, float* __restrict__ dacc) {
    const int b  = blockIdx.z;
    const int cg = blockIdx.y;        // 0..255 (32 channels per block)
    const int t  = threadIdx.x;
    const int w = t >> 6, lane = t & 63, l15 = lane & 15, g = lane >> 4;

    const int tile0 = (blockIdx.x * 4 + w) * 2;
    const bool va = (tile0     < 49);
    const bool vb = (tile0 + 1 < 49);
    const int p0a = va ? tile0 * 16 : 0;
    const int p0b = vb ? (tile0 + 1) * 16 : 0;

    const int cA = cg * 32 + l15;   // u=0 channel
    const int cB = cA + 16;         // u=1 channel
    const long long tbase = (long long)(b * NC) * TPIX;

    // teacher loads first (the HBM-heavy stream); phantom tiles issue no loads
    const float* trA = teacher + tbase + (long long)cA * TPIX;
    const float* trB = trA + 16LL * TPIX;
    float4v tvAa = {0.f,0.f,0.f,0.f}, tvAb = {0.f,0.f,0.f,0.f};
    float4v tvBa = {0.f,0.f,0.f,0.f}, tvBb = {0.f,0.f,0.f,0.f};
    if (va) { tvAa = *(const float4v*)(trA + p0a + 4 * g);
              tvBa = *(const float4v*)(trB + p0a + 4 * g); }
    if (vb) { tvAb = *(const float4v*)(trA + p0b + 4 * g);
              tvBb = *(const float4v*)(trB + p0b + 4 * g); }

    // student B-frags (L3-hot) + o
    short8 bfA[5], bfB[5];
    {
        const unsigned short* rA = studb + ((long long)(b * NC) + cA) * 160;
        const unsigned short* rB = rA + 16 * 160;
        #pragma unroll
        for (int ks = 0; ks < 5; ++ks) {
            bfA[ks] = *(const short8*)(rA + ks * 32 + g * 8);
            bfB[ks] = *(const short8*)(rB + ks * 32 + g * 8);
        }
    }
    const float oA = o[cA];
    const float oB = o[cB];

    // A-frags (M2, L2/L3-hot)
    short8 afa[5], afb[5];
    {
        const unsigned short* ra = m2 + (p0a + l15) * 160;
        const unsigned short* rb = m2 + (p0b + l15) * 160;
        #pragma unroll
        for (int ks = 0; ks < 5; ++ks) {
            afa[ks] = *(const short8*)(ra + ks * 32 + g * 8);
            afb[ks] = *(const short8*)(rb + ks * 32 + g * 8);
        }
    }

    float4v accAa = {0.f,0.f,0.f,0.f}, accAb = {0.f,0.f,0.f,0.f};
    float4v accBa = {0.f,0.f,0.f,0.f}, accBb = {0.f,0.f,0.f,0.f};
    #pragma unroll
    for (int ks = 0; ks < 5; ++ks) {
        accAa = __builtin_amdgcn_mfma_f32_16x16x32_bf16(afa[ks], bfA[ks], accAa, 0, 0, 0);
        accAb = __builtin_amdgcn_mfma_f32_16x16x32_bf16(afb[ks], bfA[ks], accAb, 0, 0, 0);
        accBa = __builtin_amdgcn_mfma_f32_16x16x32_bf16(afa[ks], bfB[ks], accBa, 0, 0, 0);
        accBb = __builtin_amdgcn_mfma_f32_16x16x32_bf16(afb[ks], bfB[ks], accBb, 0, 0, 0);
    }

    float sEa[4], sEYa[4], sEb[4], sEYb[4];
    #pragma unroll
    for (int i = 0; i < 4; ++i) {
        sEa[i] = 0.f; sEYa[i] = 0.f; sEb[i] = 0.f; sEYb[i] = 0.f;
        if (va) {
            float e0 = exp2f(fmaf(36.0673762f, tvAa[i], -oA));
            sEa[i] += e0;  sEYa[i] = fmaf(e0, accAa[i], sEYa[i]);
            float e2 = exp2f(fmaf(36.0673762f, tvBa[i], -oB));
            sEa[i] += e2;  sEYa[i] = fmaf(e2, accBa[i], sEYa[i]);
        }
        if (vb) {
            float e1 = exp2f(fmaf(36.0673762f, tvAb[i], -oA));
            sEb[i] += e1;  sEYb[i] = fmaf(e1, accAb[i], sEYb[i]);
            float e3 = exp2f(fmaf(36.0673762f, tvBb[i], -oB));
            sEb[i] += e3;  sEYb[i] = fmaf(e3, accBb[i], sEYb[i]);
        }
    }

    #pragma unroll
    for (int i = 0; i < 4; ++i) {
        float e0 = sEa[i], y0 = sEYa[i], e1 = sEb[i], y1 = sEYb[i];
        e0 += __shfl_xor(e0, 1); e0 += __shfl_xor(e0, 2); e0 += __shfl_xor(e0, 4); e0 += __shfl_xor(e0, 8);
        y0 += __shfl_xor(y0, 1); y0 += __shfl_xor(y0, 2); y0 += __shfl_xor(y0, 4); y0 += __shfl_xor(y0, 8);
        e1 += __shfl_xor(e1, 1); e1 += __shfl_xor(e1, 2); e1 += __shfl_xor(e1, 4); e1 += __shfl_xor(e1, 8);
        y1 += __shfl_xor(y1, 1); y1 += __shfl_xor(y1, 2); y1 += __shfl_xor(y1, 4); y1 += __shfl_xor(y1, 8);
        if (l15 == 0) {
            if (va) {
                atomicAdd(zacc + b * TPIX + p0a + 4 * g + i, e0);
                atomicAdd(dacc + b * TPIX + p0a + 4 * g + i, y0);
            }
            if (vb) {
                atomicAdd(zacc + b * TPIX + p0b + 4 * g + i, e1);
                atomicAdd(dacc + b * TPIX + p0b + 4 * g + i, y1);
            }
        }
    }
}

// ---------------- small fallback (raw f32 student, no studb) ---------------------------
__launch_bounds__(256, 2)
__global__ void k_main_fb(const float* __restrict__ teacher,
                          const float* __restrict__ student,
                          const float* __restrict__ center,
                          const unsigned short* __restrict__ m2,
                          float* __restrict__ zacc, float* __restrict__ dacc) {
    const int b  = blockIdx.z;
    const int cg = blockIdx.y;
    const int t  = threadIdx.x;
    const int w = t >> 6, lane = t & 63, l15 = lane & 15, g = lane >> 4;
    const int tile0 = (blockIdx.x * 4 + w) * 2;
    const bool va = (tile0     < 49);
    const bool vb = (tile0 + 1 < 49);
    const int p0a = va ? tile0 * 16 : 0;
    const int p0b = vb ? (tile0 + 1) * 16 : 0;

    short8 afa[5], afb[5];
    {
        const unsigned short* ra = m2 + (p0a + l15) * 160;
        const unsigned short* rb = m2 + (p0b + l15) * 160;
        #pragma unroll
        for (int ks = 0; ks < 5; ++ks) {
            afa[ks] = *(const short8*)(ra + ks * 32 + g * 8);
            afb[ks] = *(const short8*)(rb + ks * 32 + g * 8);
        }
    }
    float sEa[4] = {0.f,0.f,0.f,0.f}, sEYa[4] = {0.f,0.f,0.f,0.f};
    float sEb[4] = {0.f,0.f,0.f,0.f}, sEYb[4] = {0.f,0.f,0.f,0.f};
    const long long tbase = (long long)(b * NC) * TPIX;
    const long long sbase = (long long)(b * NC) * 144;
    const short8 zfrag = {0,0,0,0,0,0,0,0};

    for (int cc = 0; cc < 16; ++cc) {
        const int cA = cg * 256 + cc * 16 + l15;
        const float* sA = student + sbase + (long long)cA * 144;
        short8 bfA[5];
        #pragma unroll
        for (int ks = 0; ks < 4; ++ks)
            bfA[ks] = cvt8(*(const float4v*)(sA + ks * 32 + g * 8),
                           *(const float4v*)(sA + ks * 32 + g * 8 + 4));
        bfA[4] = (g < 2) ? cvt8(*(const float4v*)(sA + 128 + g * 8),
                                *(const float4v*)(sA + 128 + g * 8 + 4)) : zfrag;
        const float oA = fmaf(36.0673762f, center[cA], 233.7165966f);
        const float* trA = teacher + tbase + (long long)cA * TPIX;
        float4v tva = *(const float4v*)(trA + p0a + 4 * g);
        float4v tvb = *(const float4v*)(trA + p0b + 4 * g);
        float4v acca = {0.f,0.f,0.f,0.f}, accb = {0.f,0.f,0.f,0.f};
        #pragma unroll
        for (int ks = 0; ks < 5; ++ks) {
            acca = __builtin_amdgcn_mfma_f32_16x16x32_bf16(afa[ks], bfA[ks], acca, 0, 0, 0);
            accb = __builtin_amdgcn_mfma_f32_16x16x32_bf16(afb[ks], bfA[ks], accb, 0, 0, 0);
        }
        #pragma unroll
        for (int i = 0; i < 4; ++i) {
            float e0 = exp2f(fmaf(36.0673762f, tva[i], -oA));
            sEa[i] += e0;  sEYa[i] = fmaf(e0, acca[i], sEYa[i]);
            float e1 = exp2f(fmaf(36.0673762f, tvb[i], -oA));
            sEb[i] += e1;  sEYb[i] = fmaf(e1, accb[i], sEYb[i]);
        }
    }
    #pragma unroll
    for (int i = 0; i < 4; ++i) {
        float e0 = sEa[i], y0 = sEYa[i], e1 = sEb[i], y1 = sEYb[i];
        e0 += __shfl_xor(e0, 1); e0 += __shfl_xor(e0, 2); e0 += __shfl_xor(e0, 4); e0 += __shfl_xor(e0, 8);
        y0 += __shfl_xor(y0, 1); y0 += __shfl_xor(y0, 2); y0 += __shfl_xor(y0, 4); y0 += __shfl_xor(y0, 8);
        e1 += __shfl_xor(e1, 1); e1 += __shfl_xor(e1, 2); e1 += __shfl_xor(e1, 4); e1 += __shfl_xor(e1, 8);
        y1 += __shfl_xor(y1, 1); y1 += __shfl_xor(y1, 2); y1 += __shfl_xor(y1, 4); y1 += __shfl_xor(y1, 8);
        if (l15 == 0) {
            if (va) { atomicAdd(zacc + b * TPIX + p0a + 4 * g + i, e0);
                      atomicAdd(dacc + b * TPIX + p0a + 4 * g + i, y0); }
            if (vb) { atomicAdd(zacc + b * TPIX + p0b + 4 * g + i, e1);
                      atomicAdd(dacc + b * TPIX + p0b + 4 * g + i, y1); }
        }
    }
}

// ---------------- kernel 3: per-position LSE partials from bf16 studb ------------------
__launch_bounds__(256)
__global__ void k_lse_b(const unsigned short* __restrict__ studb, float* __restrict__ zpos) {
    const int cg = blockIdx.x;   // 0..3
    const int a  = blockIdx.y;
    const int b  = blockIdx.z;
    const int t  = threadIdx.x;

    const float cv = 0.7f + 0.4f * (float)a;
    const int   v0 = (int)cv;
    const float wv = cv - (float)v0;
    const float W0 = 10.f * (1.f - wv), W1 = 10.f * wv;

    float accs[25];
    #pragma unroll
    for (int p = 0; p < 25; ++p) accs[p] = 0.f;

    for (int j = 0; j < 8; ++j) {
        const int c = cg * 2048 + 256 * j + t;
        const unsigned short* row = studb + (long long)(b * NC + c) * 160 + v0 * 12;
        ushort4v h0 = *(const ushort4v*)(row + 0);
        ushort4v h1 = *(const ushort4v*)(row + 4);
        ushort4v h2 = *(const ushort4v*)(row + 8);
        ushort4v h3 = *(const ushort4v*)(row + 12);
        ushort4v h4 = *(const ushort4v*)(row + 16);
        ushort4v h5 = *(const ushort4v*)(row + 20);

        float R[12];
        #pragma unroll
        for (int u = 0; u < 4; ++u) {
            R[u]     = fmaf(W0, bf2f(h0[u]), W1 * bf2f(h3[u]));
            R[u + 4] = fmaf(W0, bf2f(h1[u]), W1 * bf2f(h4[u]));
            R[u + 8] = fmaf(W0, bf2f(h2[u]), W1 * bf2f(h5[u]));
        }
        #pragma unroll
        for (int p = 0; p < 25; ++p) {
            const float cu = 0.7f + 0.4f * (float)p;
            const int   u0 = (int)cu;
            const float wu = cu - (float)u0;
            float sc = fmaf(1.f - wu, R[u0], wu * R[u0 + 1]);       // = 10*s_common
            accs[p] += exp2f(fmaf(1.44269504f, sc, -86.5617025f));  // exp(sc - 60)
        }
    }

    #pragma unroll
    for (int p = 0; p < 25; ++p) {
        float v = accs[p];
        #pragma unroll
        for (int m = 1; m < 64; m <<= 1) v += __shfl_xor(v, m);
        accs[p] = v;
    }
    if ((t & 63) == 0) {
        #pragma unroll
        for (int p = 0; p < 25; ++p)
            atomicAdd(zpos + (b * 25 + a) * 25 + p, accs[p]);
    }
}

// fallback f32 LSE (no studb)
__launch_bounds__(256)
__global__ void k_lse(const float* __restrict__ student, float* __restrict__ zpos) {
    const int cg = blockIdx.x;
    const int a  = blockIdx.y;
    const int b  = blockIdx.z;
    const int t  = threadIdx.x;

    const float cv = 0.7f + 0.4f * (float)a;
    const int   v0 = (int)cv;
    const float wv = cv - (float)v0;
    const float W0 = 10.f * (1.f - wv), W1 = 10.f * wv;

    float accs[25];
    #pragma unroll
    for (int p = 0; p < 25; ++p) accs[p] = 0.f;

    for (int j = 0; j < 8; ++j) {
        const int c = cg * 2048 + 256 * j + t;
        const float* row = student + (long long)(b * NC + c) * 144 + v0 * 12;
        float4v r0 = *(const float4v*)(row + 0);
        float4v r1 = *(const float4v*)(row + 4);
        float4v r2 = *(const float4v*)(row + 8);
        float4v s0 = *(const float4v*)(row + 12);
        float4v s1 = *(const float4v*)(row + 16);
        float4v s2 = *(const float4v*)(row + 20);

        float R[12];
        #pragma unroll
        for (int u = 0; u < 4; ++u) {
            R[u]     = fmaf(W0, r0[u], W1 * s0[u]);
            R[u + 4] = fmaf(W0, r1[u], W1 * s1[u]);
            R[u + 8] = fmaf(W0, r2[u], W1 * s2[u]);
        }
        #pragma unroll
        for (int p = 0; p < 25; ++p) {
            const float cu = 0.7f + 0.4f * (float)p;
            const int   u0 = (int)cu;
            const float wu = cu - (float)u0;
            float sc = fmaf(1.f - wu, R[u0], wu * R[u0 + 1]);
            accs[p] += exp2f(fmaf(1.44269504f, sc, -86.5617025f));
        }
    }

    #pragma unroll
    for (int p = 0; p < 25; ++p) {
        float v = accs[p];
        #pragma unroll
        for (int m = 1; m < 64; m <<= 1) v += __shfl_xor(v, m);
        accs[p] = v;
    }
    if ((t & 63) == 0) {
        #pragma unroll
        for (int p = 0; p < 25; ++p)
            atomicAdd(zpos + (b * 25 + a) * 25 + p, accs[p]);
    }
}

// ---------------- kernel 4: final combine ----------------
__global__ void k_final(const float* __restrict__ zacc, const float* __restrict__ dacc,
                        const float* __restrict__ zpos, float* __restrict__ out) {
    __shared__ float red[8];
    int t = threadIdx.x;   // 256
    float s = 0.f;
    for (int i = t; i < 5000; i += 256) s += 60.f + logf(zpos[i]);
    for (int i = t; i < NB * TPIX; i += 256) s -= dacc[i] / zacc[i];
    for (int m = 1; m < 64; m <<= 1) s += __shfl_xor(s, m);
    if ((t & 63) == 0) red[t >> 6] = s;
    __syncthreads();
    if (t == 0) out[0] = (red[0] + red[1] + red[2] + red[3]) * (1.f / 5000.f);
}

// tiny m2-only init for the fallback path
__global__ void k_init_m2(unsigned short* __restrict__ m2) {
    int p  = blockIdx.x;           // 0..799
    int sp = threadIdx.x;          // 0..159
    int y = p / 28, x = p % 28;
    float val = 0.f;
    if (sp < 144 && p < TPIX) {
        int v = sp / 12, u = sp % 12;
        float kyv = 0.f, kxu = 0.f;
        for (int a = 0; a < 25; ++a) {
            float ctc = 0.9f + 1.05f * (float)a;
            int   i0  = (int)ctc; float wt = ctc - (float)i0;
            float Ay  = (i0 == y) ? (1.f - wt) : ((i0 + 1 == y) ? wt : 0.f);
            float Ax  = (i0 == x) ? (1.f - wt) : ((i0 + 1 == x) ? wt : 0.f);
            float csc = 0.7f + 0.4f * (float)a;
            int   j0  = (int)csc; float wsv = csc - (float)j0;
            float Bv  = (j0 == v) ? (1.f - wsv) : ((j0 + 1 == v) ? wsv : 0.f);
            float Bu  = (j0 == u) ? (1.f - wsv) : ((j0 + 1 == u) ? wsv : 0.f);
            kyv += Ay * Bv;
            kxu += Ax * Bu;
        }
        val = 10.f * kyv * kxu;
    }
    m2[p * 160 + sp] = bf16rne(val);
}

extern "C" void kernel_launch(void* const* d_in, const int* in_sizes, int n_in,
                              void* d_out, int out_size, void* d_ws, size_t ws_size,
                              hipStream_t stream) {
    const float* teacher = (const float*)d_in[0];
    const float* student = (const float*)d_in[1];
    const float* center  = (const float*)d_in[2];

    char* ws = (char*)d_ws;
    unsigned short* m2    = (unsigned short*)(ws + WS_M2);
    float*          oarr  = (float*)(ws + WS_O);
    float*          zacc  = (float*)(ws + WS_ZACC);
    float*          dacc  = (float*)(ws + WS_DACC);
    float*          zpos  = (float*)(ws + WS_ZPOS);
    unsigned short* studb = (unsigned short*)(ws + WS_STUDB);

    hipMemsetAsync(ws + WS_ZERO_OFF, 0, WS_ZERO_LEN, stream);

    if (ws_size >= (size_t)WS_NEED_MID) {
        k_prep<<<5620, 256, 0, stream>>>(student, center, studb, oarr, m2);
        k_main_s<<<dim3(7, 256, 8), 256, 0, stream>>>(teacher, m2, studb, oarr, zacc, dacc);
        k_lse_b<<<dim3(4, 25, 8), 256, 0, stream>>>(studb, zpos);
    } else {
        k_init_m2<<<800, 160, 0, stream>>>(m2);
        k_main_fb<<<dim3(7, 32, 8), 256, 0, stream>>>(teacher, student, center, m2, zacc, dacc);
        k_lse<<<dim3(4, 25, 8), 256, 0, stream>>>(student, zpos);
    }
    k_final<<<1, 256, 0, stream>>>(zacc, dacc, zpos, (float*)d_out);
}

// Round 10
// 138.883 us; speedup vs baseline: 1.8865x; 1.8865x over previous
//
#include <hip/hip_runtime.h>
#include <hip/hip_bf16.h>

typedef __attribute__((ext_vector_type(8))) short  short8;
typedef __attribute__((ext_vector_type(4))) short  short4v;
typedef __attribute__((ext_vector_type(4))) float  float4v;
typedef __attribute__((ext_vector_type(4))) unsigned short ushort4v;

#define NC    8192
#define TPIX  784      // 28*28
#define NB    8

// ws layout (bytes)
#define WS_M2    0                 // bf16 [800][160]   = 256000
#define WS_O     262144            // f32  [8192]       = 32768
#define WS_ZACC  294912            // f32  [8][784]     = 25088
#define WS_DACC  320000            // f32  [8][784]     = 25088
#define WS_ZPOS  345088            // f32  [8][25][25]  = 20000
#define WS_ZERO_OFF WS_ZACC
#define WS_ZERO_LEN 70176          // 17544 floats
#define WS_STUDB 365568            // bf16 [65536][160] = 20971520
#define WS_NEED_MID  (WS_STUDB + 65536LL*320)

__device__ __forceinline__ unsigned short bf16rne(float f) {
    unsigned int u = __float_as_uint(f);
    u = (u + 0x7FFFu + ((u >> 16) & 1u)) >> 16;
    return (unsigned short)u;
}

__device__ __forceinline__ short8 cvt8(float4v a, float4v b) {
    union { __hip_bfloat162 h[4]; short8 s; } u;
    u.h[0] = __float22bfloat162_rn(float2{a[0], a[1]});
    u.h[1] = __float22bfloat162_rn(float2{a[2], a[3]});
    u.h[2] = __float22bfloat162_rn(float2{b[0], b[1]});
    u.h[3] = __float22bfloat162_rn(float2{b[2], b[3]});
    return u.s;
}

__device__ __forceinline__ float bf2f(unsigned short h) {
    return __uint_as_float(((unsigned int)h) << 16);
}

// ---------------- kernel 1: combined prep + accumulator zeroing ------------------------
// blocks [0,5120):        student -> padded bf16 [65536][160] + o[c]
// blocks [5120,5620):     M2' = 10*K[y,v]*K[x,u], bf16 [800][160] (rows >=784 zero)
// blocks [5620,5689):     zero zacc/dacc/zpos (17544 floats)
__launch_bounds__(256)
__global__ void k_prep(const float* __restrict__ student, const float* __restrict__ center,
                       unsigned short* __restrict__ studb, float* __restrict__ o,
                       unsigned short* __restrict__ m2, float* __restrict__ zero_region) {
    const int bid = blockIdx.x;
    if (bid < 5120) {
        const int tid = bid * 256 + threadIdx.x;      // 0 .. 1310719
        const int row = tid / 20, ch = tid % 20;
        short8 hv = {0,0,0,0,0,0,0,0};
        if (ch < 18) {
            const float* src = student + (long long)row * 144 + ch * 8;
            hv = cvt8(*(const float4v*)(src), *(const float4v*)(src + 4));
        }
        *(short8*)(studb + (long long)row * 160 + ch * 8) = hv;
        if (ch == 0 && row < NC)
            o[row] = fmaf(36.0673762f, center[row], 233.7165966f);
    } else if (bid < 5620) {
        const int idx = (bid - 5120) * 256 + threadIdx.x;   // 0 .. 127999
        const int p = idx / 160, sp = idx % 160;            // p 0..799
        int y = p / 28, x = p % 28;
        float val = 0.f;
        if (sp < 144 && p < TPIX) {
            int v = sp / 12, u = sp % 12;
            float kyv = 0.f, kxu = 0.f;
            for (int a = 0; a < 25; ++a) {
                float ctc = 0.9f + 1.05f * (float)a;
                int   i0  = (int)ctc; float wt = ctc - (float)i0;
                float Ay  = (i0 == y) ? (1.f - wt) : ((i0 + 1 == y) ? wt : 0.f);
                float Ax  = (i0 == x) ? (1.f - wt) : ((i0 + 1 == x) ? wt : 0.f);
                float csc = 0.7f + 0.4f * (float)a;
                int   j0  = (int)csc; float wsv = csc - (float)j0;
                float Bv  = (j0 == v) ? (1.f - wsv) : ((j0 + 1 == v) ? wsv : 0.f);
                float Bu  = (j0 == u) ? (1.f - wsv) : ((j0 + 1 == u) ? wsv : 0.f);
                kyv += Ay * Bv;
                kxu += Ax * Bu;
            }
            val = 10.f * kyv * kxu;
        }
        m2[p * 160 + sp] = bf16rne(val);
    } else {
        const int idx = (bid - 5620) * 256 + threadIdx.x;   // 0 .. 17663
        if (idx < (int)(WS_ZERO_LEN / 4)) zero_region[idx] = 0.f;
    }
}

// ---------------- kernel 2: fused main GEMM+softmax-reduce AND per-position LSE --------
// 1-D grid of 1792 + 800 blocks, 256 thr. Block-uniform branch:
//   id < 1792 : R5/R8-proven k_main body (cc-loop of 8, register accumulators).
//   id >= 1792: k_lse_b body (studb-based LSE partials) — independent L3-hot load
//               streams that fill k_main's memory-stall bubbles instead of running
//               as a serial dispatch afterwards.
__launch_bounds__(256, 2)
__global__ void k_fused(const float* __restrict__ teacher,
                        const unsigned short* __restrict__ m2,
                        const unsigned short* __restrict__ studb,
                        const float* __restrict__ o,
                        float* __restrict__ zacc, float* __restrict__ dacc,
                        float* __restrict__ zpos) {
    const int id = blockIdx.x;
    const int t  = threadIdx.x;

    if (id < 1792) {
        // ---------------- main path ----------------
        const int px = id % 7;
        const int rem = id / 7;
        const int cg = rem % 32;          // 0..31 (256 channels per block)
        const int b  = rem / 32;          // 0..7
        const int w = t >> 6, lane = t & 63, l15 = lane & 15, g = lane >> 4;

        const int tile0 = (px * 4 + w) * 2;
        const bool va = (tile0     < 49);
        const bool vb = (tile0 + 1 < 49);
        const int p0a = va ? tile0 * 16 : 0;
        const int p0b = vb ? (tile0 + 1) * 16 : 0;

        short8 afa[5], afb[5];
        {
            const unsigned short* ra = m2 + (p0a + l15) * 160;
            const unsigned short* rb = m2 + (p0b + l15) * 160;
            #pragma unroll
            for (int ks = 0; ks < 5; ++ks) {
                afa[ks] = *(const short8*)(ra + ks * 32 + g * 8);
                afb[ks] = *(const short8*)(rb + ks * 32 + g * 8);
            }
        }

        float sEa[4] = {0.f,0.f,0.f,0.f}, sEYa[4] = {0.f,0.f,0.f,0.f};
        float sEb[4] = {0.f,0.f,0.f,0.f}, sEYb[4] = {0.f,0.f,0.f,0.f};

        const long long tbase = (long long)(b * NC) * TPIX;

        for (int cc = 0; cc < 8; ++cc) {
            const int cA = cg * 256 + cc * 32 + l15;   // u=0 channel
            const int cB = cA + 16;                    // u=1 channel

            short8 bfA[5], bfB[5];
            const unsigned short* rA = studb + ((long long)(b * NC) + cA) * 160;
            const unsigned short* rB = rA + 16 * 160;
            #pragma unroll
            for (int ks = 0; ks < 5; ++ks) {
                bfA[ks] = *(const short8*)(rA + ks * 32 + g * 8);
                bfB[ks] = *(const short8*)(rB + ks * 32 + g * 8);
            }
            const float oA = o[cA];
            const float oB = o[cB];

            const float* trA = teacher + tbase + (long long)cA * TPIX;
            const float* trB = trA + 16LL * TPIX;
            float4v tvAa = *(const float4v*)(trA + p0a + 4 * g);
            float4v tvAb = *(const float4v*)(trA + p0b + 4 * g);
            float4v tvBa = *(const float4v*)(trB + p0a + 4 * g);
            float4v tvBb = *(const float4v*)(trB + p0b + 4 * g);

            float4v accAa = {0.f,0.f,0.f,0.f}, accAb = {0.f,0.f,0.f,0.f};
            float4v accBa = {0.f,0.f,0.f,0.f}, accBb = {0.f,0.f,0.f,0.f};
            #pragma unroll
            for (int ks = 0; ks < 5; ++ks) {
                accAa = __builtin_amdgcn_mfma_f32_16x16x32_bf16(afa[ks], bfA[ks], accAa, 0, 0, 0);
                accAb = __builtin_amdgcn_mfma_f32_16x16x32_bf16(afb[ks], bfA[ks], accAb, 0, 0, 0);
                accBa = __builtin_amdgcn_mfma_f32_16x16x32_bf16(afa[ks], bfB[ks], accBa, 0, 0, 0);
                accBb = __builtin_amdgcn_mfma_f32_16x16x32_bf16(afb[ks], bfB[ks], accBb, 0, 0, 0);
            }

            #pragma unroll
            for (int i = 0; i < 4; ++i) {
                float e0 = exp2f(fmaf(36.0673762f, tvAa[i], -oA));
                sEa[i] += e0;  sEYa[i] = fmaf(e0, accAa[i], sEYa[i]);
                float e1 = exp2f(fmaf(36.0673762f, tvAb[i], -oA));
                sEb[i] += e1;  sEYb[i] = fmaf(e1, accAb[i], sEYb[i]);
                float e2 = exp2f(fmaf(36.0673762f, tvBa[i], -oB));
                sEa[i] += e2;  sEYa[i] = fmaf(e2, accBa[i], sEYa[i]);
                float e3 = exp2f(fmaf(36.0673762f, tvBb[i], -oB));
                sEb[i] += e3;  sEYb[i] = fmaf(e3, accBb[i], sEYb[i]);
            }
        }

        #pragma unroll
        for (int i = 0; i < 4; ++i) {
            float e0 = sEa[i], y0 = sEYa[i], e1 = sEb[i], y1 = sEYb[i];
            e0 += __shfl_xor(e0, 1); e0 += __shfl_xor(e0, 2); e0 += __shfl_xor(e0, 4); e0 += __shfl_xor(e0, 8);
            y0 += __shfl_xor(y0, 1); y0 += __shfl_xor(y0, 2); y0 += __shfl_xor(y0, 4); y0 += __shfl_xor(y0, 8);
            e1 += __shfl_xor(e1, 1); e1 += __shfl_xor(e1, 2); e1 += __shfl_xor(e1, 4); e1 += __shfl_xor(e1, 8);
            y1 += __shfl_xor(y1, 1); y1 += __shfl_xor(y1, 2); y1 += __shfl_xor(y1, 4); y1 += __shfl_xor(y1, 8);
            if (l15 == 0) {
                if (va) {
                    atomicAdd(zacc + b * TPIX + p0a + 4 * g + i, e0);
                    atomicAdd(dacc + b * TPIX + p0a + 4 * g + i, y0);
                }
                if (vb) {
                    atomicAdd(zacc + b * TPIX + p0b + 4 * g + i, e1);
                    atomicAdd(dacc + b * TPIX + p0b + 4 * g + i, y1);
                }
            }
        }
    } else {
        // ---------------- LSE path ----------------
        const int lid = id - 1792;        // 0..799
        const int cg = lid % 4;
        const int a  = (lid / 4) % 25;
        const int b  = lid / 100;

        const float cv = 0.7f + 0.4f * (float)a;
        const int   v0 = (int)cv;
        const float wv = cv - (float)v0;
        const float W0 = 10.f * (1.f - wv), W1 = 10.f * wv;

        float accs[25];
        #pragma unroll
        for (int p = 0; p < 25; ++p) accs[p] = 0.f;

        for (int j = 0; j < 8; ++j) {
            const int c = cg * 2048 + 256 * j + t;
            const unsigned short* row = studb + (long long)(b * NC + c) * 160 + v0 * 12;
            ushort4v h0 = *(const ushort4v*)(row + 0);
            ushort4v h1 = *(const ushort4v*)(row + 4);
            ushort4v h2 = *(const ushort4v*)(row + 8);
            ushort4v h3 = *(const ushort4v*)(row + 12);
            ushort4v h4 = *(const ushort4v*)(row + 16);
            ushort4v h5 = *(const ushort4v*)(row + 20);

            float R[12];
            #pragma unroll
            for (int u = 0; u < 4; ++u) {
                R[u]     = fmaf(W0, bf2f(h0[u]), W1 * bf2f(h3[u]));
                R[u + 4] = fmaf(W0, bf2f(h1[u]), W1 * bf2f(h4[u]));
                R[u + 8] = fmaf(W0, bf2f(h2[u]), W1 * bf2f(h5[u]));
            }
            #pragma unroll
            for (int p = 0; p < 25; ++p) {
                const float cu = 0.7f + 0.4f * (float)p;
                const int   u0 = (int)cu;
                const float wu = cu - (float)u0;
                float sc = fmaf(1.f - wu, R[u0], wu * R[u0 + 1]);       // = 10*s_common
                accs[p] += exp2f(fmaf(1.44269504f, sc, -86.5617025f));  // exp(sc - 60)
            }
        }

        #pragma unroll
        for (int p = 0; p < 25; ++p) {
            float v = accs[p];
            #pragma unroll
            for (int m = 1; m < 64; m <<= 1) v += __shfl_xor(v, m);
            accs[p] = v;
        }
        if ((t & 63) == 0) {
            #pragma unroll
            for (int p = 0; p < 25; ++p)
                atomicAdd(zpos + (b * 25 + a) * 25 + p, accs[p]);
        }
    }
}

// ---------------- small fallback path (raw f32 student, no studb) ----------------------
__global__ void k_init_m2(unsigned short* __restrict__ m2) {
    int p  = blockIdx.x;           // 0..799
    int sp = threadIdx.x;          // 0..159
    int y = p / 28, x = p % 28;
    float val = 0.f;
    if (sp < 144 && p < TPIX) {
        int v = sp / 12, u = sp % 12;
        float kyv = 0.f, kxu = 0.f;
        for (int a = 0; a < 25; ++a) {
            float ctc = 0.9f + 1.05f * (float)a;
            int   i0  = (int)ctc; float wt = ctc - (float)i0;
            float Ay  = (i0 == y) ? (1.f - wt) : ((i0 + 1 == y) ? wt : 0.f);
            float Ax  = (i0 == x) ? (1.f - wt) : ((i0 + 1 == x) ? wt : 0.f);
            float csc = 0.7f + 0.4f * (float)a;
            int   j0  = (int)csc; float wsv = csc - (float)j0;
            float Bv  = (j0 == v) ? (1.f - wsv) : ((j0 + 1 == v) ? wsv : 0.f);
            float Bu  = (j0 == u) ? (1.f - wsv) : ((j0 + 1 == u) ? wsv : 0.f);
            kyv += Ay * Bv;
            kxu += Ax * Bu;
        }
        val = 10.f * kyv * kxu;
    }
    m2[p * 160 + sp] = bf16rne(val);
}

__launch_bounds__(256, 2)
__global__ void k_main_fb(const float* __restrict__ teacher,
                          const float* __restrict__ student,
                          const float* __restrict__ center,
                          const unsigned short* __restrict__ m2,
                          float* __restrict__ zacc, float* __restrict__ dacc) {
    const int b  = blockIdx.z;
    const int cg = blockIdx.y;
    const int t  = threadIdx.x;
    const int w = t >> 6, lane = t & 63, l15 = lane & 15, g = lane >> 4;
    const int tile0 = (blockIdx.x * 4 + w) * 2;
    const bool va = (tile0     < 49);
    const bool vb = (tile0 + 1 < 49);
    const int p0a = va ? tile0 * 16 : 0;
    const int p0b = vb ? (tile0 + 1) * 16 : 0;

    short8 afa[5], afb[5];
    {
        const unsigned short* ra = m2 + (p0a + l15) * 160;
        const unsigned short* rb = m2 + (p0b + l15) * 160;
        #pragma unroll
        for (int ks = 0; ks < 5; ++ks) {
            afa[ks] = *(const short8*)(ra + ks * 32 + g * 8);
            afb[ks] = *(const short8*)(rb + ks * 32 + g * 8);
        }
    }
    float sEa[4] = {0.f,0.f,0.f,0.f}, sEYa[4] = {0.f,0.f,0.f,0.f};
    float sEb[4] = {0.f,0.f,0.f,0.f}, sEYb[4] = {0.f,0.f,0.f,0.f};
    const long long tbase = (long long)(b * NC) * TPIX;
    const long long sbase = (long long)(b * NC) * 144;
    const short8 zfrag = {0,0,0,0,0,0,0,0};

    for (int cc = 0; cc < 16; ++cc) {
        const int cA = cg * 256 + cc * 16 + l15;
        const float* sA = student + sbase + (long long)cA * 144;
        short8 bfA[5];
        #pragma unroll
        for (int ks = 0; ks < 4; ++ks)
            bfA[ks] = cvt8(*(const float4v*)(sA + ks * 32 + g * 8),
                           *(const float4v*)(sA + ks * 32 + g * 8 + 4));
        bfA[4] = (g < 2) ? cvt8(*(const float4v*)(sA + 128 + g * 8),
                                *(const float4v*)(sA + 128 + g * 8 + 4)) : zfrag;
        const float oA = fmaf(36.0673762f, center[cA], 233.7165966f);
        const float* trA = teacher + tbase + (long long)cA * TPIX;
        float4v tva = *(const float4v*)(trA + p0a + 4 * g);
        float4v tvb = *(const float4v*)(trA + p0b + 4 * g);
        float4v acca = {0.f,0.f,0.f,0.f}, accb = {0.f,0.f,0.f,0.f};
        #pragma unroll
        for (int ks = 0; ks < 5; ++ks) {
            acca = __builtin_amdgcn_mfma_f32_16x16x32_bf16(afa[ks], bfA[ks], acca, 0, 0, 0);
            accb = __builtin_amdgcn_mfma_f32_16x16x32_bf16(afb[ks], bfA[ks], accb, 0, 0, 0);
        }
        #pragma unroll
        for (int i = 0; i < 4; ++i) {
            float e0 = exp2f(fmaf(36.0673762f, tva[i], -oA));
            sEa[i] += e0;  sEYa[i] = fmaf(e0, acca[i], sEYa[i]);
            float e1 = exp2f(fmaf(36.0673762f, tvb[i], -oA));
            sEb[i] += e1;  sEYb[i] = fmaf(e1, accb[i], sEYb[i]);
        }
    }
    #pragma unroll
    for (int i = 0; i < 4; ++i) {
        float e0 = sEa[i], y0 = sEYa[i], e1 = sEb[i], y1 = sEYb[i];
        e0 += __shfl_xor(e0, 1); e0 += __shfl_xor(e0, 2); e0 += __shfl_xor(e0, 4); e0 += __shfl_xor(e0, 8);
        y0 += __shfl_xor(y0, 1); y0 += __shfl_xor(y0, 2); y0 += __shfl_xor(y0, 4); y0 += __shfl_xor(y0, 8);
        e1 += __shfl_xor(e1, 1); e1 += __shfl_xor(e1, 2); e1 += __shfl_xor(e1, 4); e1 += __shfl_xor(e1, 8);
        y1 += __shfl_xor(y1, 1); y1 += __shfl_xor(y1, 2); y1 += __shfl_xor(y1, 4); y1 += __shfl_xor(y1, 8);
        if (l15 == 0) {
            if (va) { atomicAdd(zacc + b * TPIX + p0a + 4 * g + i, e0);
                      atomicAdd(dacc + b * TPIX + p0a + 4 * g + i, y0); }
            if (vb) { atomicAdd(zacc + b * TPIX + p0b + 4 * g + i, e1);
                      atomicAdd(dacc + b * TPIX + p0b + 4 * g + i, y1); }
        }
    }
}

__launch_bounds__(256)
__global__ void k_lse(const float* __restrict__ student, float* __restrict__ zpos) {
    const int cg = blockIdx.x;
    const int a  = blockIdx.y;
    const int b  = blockIdx.z;
    const int t  = threadIdx.x;

    const float cv = 0.7f + 0.4f * (float)a;
    const int   v0 = (int)cv;
    const float wv = cv - (float)v0;
    const float W0 = 10.f * (1.f - wv), W1 = 10.f * wv;

    float accs[25];
    #pragma unroll
    for (int p = 0; p < 25; ++p) accs[p] = 0.f;

    for (int j = 0; j < 8; ++j) {
        const int c = cg * 2048 + 256 * j + t;
        const float* row = student + (long long)(b * NC + c) * 144 + v0 * 12;
        float4v r0 = *(const float4v*)(row + 0);
        float4v r1 = *(const float4v*)(row + 4);
        float4v r2 = *(const float4v*)(row + 8);
        float4v s0 = *(const float4v*)(row + 12);
        float4v s1 = *(const float4v*)(row + 16);
        float4v s2 = *(const float4v*)(row + 20);

        float R[12];
        #pragma unroll
        for (int u = 0; u < 4; ++u) {
            R[u]     = fmaf(W0, r0[u], W1 * s0[u]);
            R[u + 4] = fmaf(W0, r1[u], W1 * s1[u]);
            R[u + 8] = fmaf(W0, r2[u], W1 * s2[u]);
        }
        #pragma unroll
        for (int p = 0; p < 25; ++p) {
            const float cu = 0.7f + 0.4f * (float)p;
            const int   u0 = (int)cu;
            const float wu = cu - (float)u0;
            float sc = fmaf(1.f - wu, R[u0], wu * R[u0 + 1]);
            accs[p] += exp2f(fmaf(1.44269504f, sc, -86.5617025f));
        }
    }

    #pragma unroll
    for (int p = 0; p < 25; ++p) {
        float v = accs[p];
        #pragma unroll
        for (int m = 1; m < 64; m <<= 1) v += __shfl_xor(v, m);
        accs[p] = v;
    }
    if ((t & 63) == 0) {
        #pragma unroll
        for (int p = 0; p < 25; ++p)
            atomicAdd(zpos + (b * 25 + a) * 25 + p, accs[p]);
    }
}

// ---------------- kernel 3: final combine ----------------
__global__ void k_final(const float* __restrict__ zacc, const float* __restrict__ dacc,
                        const float* __restrict__ zpos, float* __restrict__ out) {
    __shared__ float red[8];
    int t = threadIdx.x;   // 256
    float s = 0.f;
    for (int i = t; i < 5000; i += 256) s += 60.f + logf(zpos[i]);
    for (int i = t; i < NB * TPIX; i += 256) s -= dacc[i] / zacc[i];
    for (int m = 1; m < 64; m <<= 1) s += __shfl_xor(s, m);
    if ((t & 63) == 0) red[t >> 6] = s;
    __syncthreads();
    if (t == 0) out[0] = (red[0] + red[1] + red[2] + red[3]) * (1.f / 5000.f);
}

extern "C" void kernel_launch(void* const* d_in, const int* in_sizes, int n_in,
                              void* d_out, int out_size, void* d_ws, size_t ws_size,
                              hipStream_t stream) {
    const float* teacher = (const float*)d_in[0];
    const float* student = (const float*)d_in[1];
    const float* center  = (const float*)d_in[2];

    char* ws = (char*)d_ws;
    unsigned short* m2    = (unsigned short*)(ws + WS_M2);
    float*          oarr  = (float*)(ws + WS_O);
    float*          zacc  = (float*)(ws + WS_ZACC);
    float*          dacc  = (float*)(ws + WS_DACC);
    float*          zpos  = (float*)(ws + WS_ZPOS);
    unsigned short* studb = (unsigned short*)(ws + WS_STUDB);

    if (ws_size >= (size_t)WS_NEED_MID) {
        k_prep<<<5689, 256, 0, stream>>>(student, center, studb, oarr, m2,
                                         (float*)(ws + WS_ZERO_OFF));
        k_fused<<<2592, 256, 0, stream>>>(teacher, m2, studb, oarr, zacc, dacc, zpos);
    } else {
        hipMemsetAsync(ws + WS_ZERO_OFF, 0, WS_ZERO_LEN, stream);
        k_init_m2<<<800, 160, 0, stream>>>(m2);
        k_main_fb<<<dim3(7, 32, 8), 256, 0, stream>>>(teacher, student, center, m2, zacc, dacc);
        k_lse<<<dim3(4, 25, 8), 256, 0, stream>>>(student, zpos);
    }
    k_final<<<1, 256, 0, stream>>>(zacc, dacc, zpos, (float*)d_out);
}